// Round 13
// baseline (146.126 us; speedup 1.0000x reference)
//
#include <hip/hip_runtime.h>
#include <hip/hip_bf16.h>
#include <stdint.h>

typedef short short8 __attribute__((ext_vector_type(8)));
typedef float f32x4  __attribute__((ext_vector_type(4)));

static constexpr int O_TOT = 28672;
static constexpr int K_TOT = 8192;
static constexpr int M_ROWS = 8;
static constexpr int KW = 1024;            // packed int32 words per output row

// workspace: flag @0, staged x @WS_X, group sums @WS_SG
static constexpr size_t WS_X    = 4096;
static constexpr size_t WS_SG   = WS_X + (size_t)8 * K_TOT * 2;   // 128KB staged x
static constexpr size_t WS_NEED_V13 = WS_SG + 64 * 8 * 4 + 64;    // ~135KB

// mode: 0 = bf16, 1 = fp16, 2 = f32
__device__ __forceinline__ float dec16(uint16_t u, int mode) {
  if (mode == 0) {
    union { uint32_t i; float f; } v; v.i = ((uint32_t)u) << 16; return v.f;
  } else {
    union { uint16_t u; _Float16 h; } v; v.u = u; return (float)v.h;
  }
}
__device__ __forceinline__ float u2f(uint32_t u) {
  union { uint32_t i; float f; } v; v.i = u; return v.f;
}
__device__ __forceinline__ uint16_t f2bf_bits(float f) {
  union { __hip_bfloat16 b; uint16_t u; } v; v.b = __float2bfloat16(f); return v.u;
}
__device__ __forceinline__ uint16_t f2h_bits(float f) {
  union { uint16_t u; _Float16 h; } v; v.h = (_Float16)f; return v.u;
}

// wave-level sniff of x[0..1023] (verified R3-R12); uniform across lanes
__device__ __forceinline__ int wave_sniff(const uint16_t* __restrict__ x) {
  const int t = threadIdx.x & 63;
  int ce = 0, co = 0;
  #pragma unroll
  for (int i = 0; i < 2; ++i) {
    const uint4 u = *reinterpret_cast<const uint4*>(x + (size_t)(t + 64 * i) * 8);
    const uint32_t d[4] = {u.x, u.y, u.z, u.w};
    #pragma unroll
    for (int j = 0; j < 4; ++j) {
      const int elo = (d[j] >> 7)  & 0xFF;
      const int ehi = (d[j] >> 23) & 0xFF;
      ce += (elo >= 118 && elo <= 131);
      co += (ehi >= 118 && ehi <= 131);
    }
  }
  for (int d = 32; d; d >>= 1) { ce += __shfl_xor(ce, d); co += __shfl_xor(co, d); }
  return (ce > 358 && co > 358) ? 0 : ((co > 358) ? 2 : 1);
}

// --- prep_fast: 128 blocks x 64 threads; sniff + decode/permute x + group sums (shuffle-only) ---
__global__ __launch_bounds__(64)
void prep_fast_kernel(const uint16_t* __restrict__ x16, uint8_t* __restrict__ ws) {
  const int t = threadIdx.x;
  const int mode = wave_sniff(x16);
  if (blockIdx.x == 0 && t == 0) *reinterpret_cast<int*>(ws) = mode;

  const int tid = blockIdx.x * 64 + t;              // 8192 threads total
  const int r = tid >> 10, wb = tid & 1023;
  uint16_t s[8];
  if (mode == 2) {
    const float* xF = (const float*)x16;
    #pragma unroll
    for (int j = 0; j < 8; ++j) s[j] = f2bf_bits(xF[(size_t)r * K_TOT + wb * 8 + j]);
  } else {
    const uint4 u = *reinterpret_cast<const uint4*>(x16 + (size_t)r * K_TOT + wb * 8);
    const uint32_t d[4] = {u.x, u.y, u.z, u.w};
    #pragma unroll
    for (int j = 0; j < 8; ++j) {
      const uint16_t raw = (j & 1) ? (uint16_t)(d[j >> 1] >> 16) : (uint16_t)(d[j >> 1] & 0xffffu);
      s[j] = (mode == 0) ? raw : f2bf_bits(dec16(raw, 1));
    }
  }
  uint16_t p[8];
  p[0] = s[0]; p[1] = s[4]; p[2] = s[1]; p[3] = s[5];
  p[4] = s[2]; p[5] = s[6]; p[6] = s[3]; p[7] = s[7];
  uint4 o;
  o.x = (uint32_t)p[0] | ((uint32_t)p[1] << 16);
  o.y = (uint32_t)p[2] | ((uint32_t)p[3] << 16);
  o.z = (uint32_t)p[4] | ((uint32_t)p[5] << 16);
  o.w = (uint32_t)p[6] | ((uint32_t)p[7] << 16);
  *reinterpret_cast<uint4*>((uint16_t*)(ws + WS_X) + (size_t)r * K_TOT + wb * 8) = o;

  // group sum: 16 consecutive threads = one (group, row); butterfly shuffle
  float loc = 0.f;
  #pragma unroll
  for (int j = 0; j < 8; ++j) loc += dec16(p[j], 0);
  loc += __shfl_xor(loc, 1);
  loc += __shfl_xor(loc, 2);
  loc += __shfl_xor(loc, 4);
  loc += __shfl_xor(loc, 8);
  if ((t & 15) == 0) {
    const int G = wb >> 4;
    ((float*)(ws + WS_SG))[G * 8 + r] = loc;
  }
}

// ================= v13 main: full-K per block, LDS dbuf, reg-accum, fused epilogue ==========

#define MFMA_T(T, CUR, QC, QZC)                                                \
  do {                                                                         \
    const uint4 a0 = xl[CUR][cc * 129 + 16 * (T) + 4 * g4 + 0];                \
    const uint4 a1 = xl[CUR][cc * 129 + 16 * (T) + 4 * g4 + 1];                \
    const uint4 a2 = xl[CUR][cc * 129 + 16 * (T) + 4 * g4 + 2];                \
    const uint4 a3 = xl[CUR][cc * 129 + 16 * (T) + 4 * g4 + 3];                \
    const f32x4 sgv = *reinterpret_cast<const f32x4*>(&sgl[CUR][(T) * 8 + (g4 & 1) * 4]); \
    f32x4 tmp = {0.f, 0.f, 0.f, 0.f};                                          \
    const uint32_t wvv[4] = {QC[T].x, QC[T].y, QC[T].z, QC[T].w};              \
    const uint4   av[4] = {a0, a1, a2, a3};                                    \
    _Pragma("unroll")                                                          \
    for (int u = 0; u < 4; ++u) {                                              \
      union { uint32_t d[4]; short8 s; } bb;                                   \
      bb.d[0] = ( wvv[u]        & 0x000F000Fu) | 0x43004300u;                  \
      bb.d[1] = ((wvv[u] >> 4)  & 0x000F000Fu) | 0x43004300u;                  \
      bb.d[2] = ((wvv[u] >> 8)  & 0x000F000Fu) | 0x43004300u;                  \
      bb.d[3] = ((wvv[u] >> 12) & 0x000F000Fu) | 0x43004300u;                  \
      union { uint4 q; short8 s; } aa; aa.q = av[u];                           \
      tmp = __builtin_amdgcn_mfma_f32_16x16x32_bf16(aa.s, bb.s, tmp, 0, 0, 0); \
    }                                                                          \
    const float zf = (float)((QZC >> ((T) * 4)) & 15u);                        \
    const float cz = 128.0f + zf;                                              \
    D[0] += sv[(T)] * (tmp[0] - cz * sgv[0]);                                  \
    D[1] += sv[(T)] * (tmp[1] - cz * sgv[1]);                                  \
    D[2] += sv[(T)] * (tmp[2] - cz * sgv[2]);                                  \
    D[3] += sv[(T)] * (tmp[3] - cz * sgv[3]);                                  \
  } while (0)

#define CHUNK_BODY(CK, CUR, NXT, QC, QN, SC0, SC1, SN0, SN1, QZC, QZN, LAST)   \
  do {                                                                         \
    float sv[8];                                                               \
    if (mode == 2) {                                                           \
      sv[0] = u2f(SC0.x); sv[1] = u2f(SC0.y); sv[2] = u2f(SC0.z); sv[3] = u2f(SC0.w); \
      sv[4] = u2f(SC1.x); sv[5] = u2f(SC1.y); sv[6] = u2f(SC1.z); sv[7] = u2f(SC1.w); \
    } else {                                                                   \
      const uint32_t sd[4] = {SC0.x, SC0.y, SC0.z, SC0.w};                     \
      _Pragma("unroll")                                                        \
      for (int j = 0; j < 4; ++j) {                                            \
        sv[2*j]   = dec16((uint16_t)(sd[j] & 0xffffu), mode);                  \
        sv[2*j+1] = dec16((uint16_t)(sd[j] >> 16), mode);                      \
      }                                                                        \
    }                                                                          \
    uint4 xr0, xr1, xr2, xr3; float sgn = 0.f;                                 \
    if (!(LAST)) {                                                             \
      const int nk = (CK) + 1;                                                 \
      /* x loads FIRST (L2-hot, retire early under in-order vmcnt) */          \
      xr0 = src[(size_t)r0 * 1024 + nk * 128 + w0];                            \
      xr1 = src[(size_t)r1 * 1024 + nk * 128 + w1];                            \
      xr2 = src[(size_t)r2 * 1024 + nk * 128 + w2];                            \
      xr3 = src[(size_t)r3 * 1024 + nk * 128 + w3];                            \
      if (t < 64) sgn = sgpf[nk * 64 + t];                                     \
      /* then the HBM q stream for chunk nk */                                 \
      _Pragma("unroll")                                                        \
      for (int T = 0; T < 8; ++T)                                              \
        QN[T] = *reinterpret_cast<const uint4*>(qp + nk * 128 + 16 * T + 4 * g4); \
      if (mode == 2) {                                                         \
        const uint4* sp = (const uint4*)((const float*)sc16 + (size_t)cg * 64 + nk * 8); \
        SN0 = sp[0]; SN1 = sp[1];                                              \
      } else {                                                                 \
        SN0 = *reinterpret_cast<const uint4*>(sc16 + (size_t)cg * 64 + nk * 8);\
      }                                                                        \
      QZN = qzeros[cg * 8 + nk];                                               \
    }                                                                          \
    MFMA_T(0, CUR, QC, QZC);                                                   \
    MFMA_T(1, CUR, QC, QZC);                                                   \
    MFMA_T(2, CUR, QC, QZC);                                                   \
    MFMA_T(3, CUR, QC, QZC);                                                   \
    if (!(LAST)) {                                                             \
      xl[NXT][r0 * 129 + w0] = xr0;                                            \
      xl[NXT][r1 * 129 + w1] = xr1;                                            \
      xl[NXT][r2 * 129 + w2] = xr2;                                            \
      xl[NXT][r3 * 129 + w3] = xr3;                                            \
      if (t < 64) sgl[NXT][t] = sgn;                                           \
    }                                                                          \
    MFMA_T(4, CUR, QC, QZC);                                                   \
    MFMA_T(5, CUR, QC, QZC);                                                   \
    MFMA_T(6, CUR, QC, QZC);                                                   \
    MFMA_T(7, CUR, QC, QZC);                                                   \
    if (!(LAST)) __syncthreads();                                              \
  } while (0)

__global__ __launch_bounds__(256)
void wq_mfma_fullk_kernel(const uint16_t* __restrict__ x16,
                          const uint32_t* __restrict__ qweight,
                          const uint32_t* __restrict__ qzeros,
                          const uint16_t* __restrict__ sc16,
                          const uint16_t* __restrict__ b16,
                          void* __restrict__ outv,
                          const uint8_t* __restrict__ ws)
{
  __shared__ __align__(16) uint4 xl[2][8 * 129];   // 33KB (x dbuf, +1 uint4 row pad)
  __shared__ float sgl[2][64];
  const int mode = *reinterpret_cast<const int*>(ws);
  const int t = threadIdx.x, wid = t >> 6, lane = t & 63;
  const int c = lane & 15, g4 = lane >> 4, cc = lane & 7;
  const int cg = blockIdx.x * 64 + wid * 16 + c;

  const uint4*  src  = (const uint4*)(ws + WS_X);
  const float*  sgpf = (const float*)(ws + WS_SG);
  const uint32_t* qp = qweight + (size_t)cg * KW;

  // staging indices (thread-fixed)
  const int i0 = t, i1 = 256 + t, i2 = 512 + t, i3 = 768 + t;
  const int r0 = i0 >> 7, w0 = i0 & 127;
  const int r1 = i1 >> 7, w1 = i1 & 127;
  const int r2 = i2 >> 7, w2 = i2 & 127;
  const int r3 = i3 >> 7, w3 = i3 & 127;

  // ---- prologue: chunk 0 ----
  const uint4 p0 = src[(size_t)r0 * 1024 + w0];
  const uint4 p1 = src[(size_t)r1 * 1024 + w1];
  const uint4 p2 = src[(size_t)r2 * 1024 + w2];
  const uint4 p3 = src[(size_t)r3 * 1024 + w3];
  const float sg0 = (t < 64) ? sgpf[t] : 0.f;

  uint4 qA[8], qB[8];
  #pragma unroll
  for (int T = 0; T < 8; ++T)
    qA[T] = *reinterpret_cast<const uint4*>(qp + 16 * T + 4 * g4);

  uint4 sA0 = {0,0,0,0}, sA1 = {0,0,0,0}, sB0 = {0,0,0,0}, sB1 = {0,0,0,0};
  if (mode == 2) {
    const uint4* sp = (const uint4*)((const float*)sc16 + (size_t)cg * 64);
    sA0 = sp[0]; sA1 = sp[1];
  } else {
    sA0 = *reinterpret_cast<const uint4*>(sc16 + (size_t)cg * 64);
  }
  uint32_t qzA = qzeros[cg * 8], qzB = 0;
  const float biasf = (mode == 2) ? ((const float*)b16)[cg] : dec16(b16[cg], mode);

  xl[0][r0 * 129 + w0] = p0;
  xl[0][r1 * 129 + w1] = p1;
  xl[0][r2 * 129 + w2] = p2;
  xl[0][r3 * 129 + w3] = p3;
  if (t < 64) sgl[0][t] = sg0;
  __syncthreads();

  f32x4 D = {0.f, 0.f, 0.f, 0.f};

  CHUNK_BODY(0, 0, 1, qA, qB, sA0, sA1, sB0, sB1, qzA, qzB, false);
  CHUNK_BODY(1, 1, 0, qB, qA, sB0, sB1, sA0, sA1, qzB, qzA, false);
  CHUNK_BODY(2, 0, 1, qA, qB, sA0, sA1, sB0, sB1, qzA, qzB, false);
  CHUNK_BODY(3, 1, 0, qB, qA, sB0, sB1, sA0, sA1, qzB, qzA, false);
  CHUNK_BODY(4, 0, 1, qA, qB, sA0, sA1, sB0, sB1, qzA, qzB, false);
  CHUNK_BODY(5, 1, 0, qB, qA, sB0, sB1, sA0, sA1, qzB, qzA, false);
  CHUNK_BODY(6, 0, 1, qA, qB, sA0, sA1, sB0, sB1, qzA, qzB, false);
  CHUNK_BODY(7, 1, 0, qB, qA, sB0, sB1, sA0, sA1, qzB, qzA, true);

  // ---- fused epilogue: bias + encode + direct store (rows 0..7) ----
  if (g4 < 2) {
    #pragma unroll
    for (int reg = 0; reg < 4; ++reg) {
      const int r = g4 * 4 + reg;                  // D row = (lane>>4)*4 + reg (m89)
      const float v = D[reg] + biasf;
      const size_t idx = (size_t)r * O_TOT + cg;
      if (mode == 0)      ((__hip_bfloat16*)outv)[idx] = __float2bfloat16(v);
      else if (mode == 1) ((uint16_t*)outv)[idx] = f2h_bits(v);
      else                ((float*)outv)[idx] = v;
    }
  }
}

#undef CHUNK_BODY
#undef MFMA_T

// ============ bottom-tier fallback (verified R4) ============
__global__ void sniff_kernel(const uint16_t* __restrict__ x, int* __restrict__ flag) {
  if (threadIdx.x == 0) { }
  const int mode = wave_sniff(x);
  if (threadIdx.x == 0) *flag = mode;
}

static constexpr int NTHR = 512, O_PER_IT = 2, ITERS = 14, NBLK = 1024;
__global__ __launch_bounds__(NTHR, 1)
void wq_fallback_kernel(const uint16_t* __restrict__ x16,
                        const uint32_t* __restrict__ qweight,
                        const uint32_t* __restrict__ qzeros,
                        const uint16_t* __restrict__ sc16,
                        const uint16_t* __restrict__ b16,
                        void* __restrict__ outv,
                        const int* __restrict__ flag)
{
  __shared__ float lds[O_PER_IT][M_ROWS][NTHR];
  const int mode = *flag;
  const int t = threadIdx.x;
  const float* xF  = (const float*)x16;
  const float* scF = (const float*)sc16;
  const float* bF  = (const float*)b16;
  float xf[M_ROWS][16];
  {
    const int kbase = 16 * t;
    if (mode == 2) {
      #pragma unroll
      for (int n = 0; n < M_ROWS; ++n)
        #pragma unroll
        for (int i = 0; i < 16; ++i) xf[n][i] = xF[(size_t)n * K_TOT + kbase + i];
    } else {
      #pragma unroll
      for (int n = 0; n < M_ROWS; ++n)
        #pragma unroll
        for (int i = 0; i < 16; ++i) xf[n][i] = dec16(x16[(size_t)n * K_TOT + kbase + i], mode);
    }
  }
  const int g = t >> 3, zsh = (g & 7) * 4, zword = g >> 3;
  for (int it = 0; it < ITERS; ++it) {
    const int obase = blockIdx.x * (ITERS * O_PER_IT) + it * O_PER_IT;
    #pragma unroll
    for (int oi = 0; oi < O_PER_IT; ++oi) {
      const int o = obase + oi;
      const uint32_t zw = qzeros[o * 8 + zword];
      const float z = (float)((zw >> zsh) & 15u);
      const float s = (mode == 2) ? scF[o * 64 + g] : dec16(sc16[o * 64 + g], mode);
      const uint32_t w0 = qweight[(size_t)o * KW + 2 * t];
      const uint32_t w1 = qweight[(size_t)o * KW + 2 * t + 1];
      float d[M_ROWS];
      #pragma unroll
      for (int n = 0; n < M_ROWS; ++n) d[n] = 0.f;
      const uint32_t wvv[2] = { w0, w1 };
      #pragma unroll
      for (int w = 0; w < 2; ++w)
        #pragma unroll
        for (int j = 0; j < 8; ++j) {
          const float q = (float)((wvv[w] >> (4 * j)) & 15u);
          const float wgt = s * (q - z);
          #pragma unroll
          for (int n = 0; n < M_ROWS; ++n) d[n] = fmaf(wgt, xf[n][8 * w + j], d[n]);
        }
      #pragma unroll
      for (int n = 0; n < M_ROWS; ++n) lds[oi][n][t] = d[n];
    }
    __syncthreads();
    {
      const int wvid = t >> 6, lanei = t & 63;
      #pragma unroll
      for (int cc2 = 0; cc2 < 2; ++cc2) {
        const int p = 2 * wvid + cc2, oi = p >> 3, n = p & 7;
        float v = 0.f;
        #pragma unroll
        for (int i = 0; i < 8; ++i) v += lds[oi][n][lanei + 64 * i];
        v += __shfl_xor(v, 32); v += __shfl_xor(v, 16); v += __shfl_xor(v, 8);
        v += __shfl_xor(v, 4);  v += __shfl_xor(v, 2);  v += __shfl_xor(v, 1);
        if (lanei == 0) {
          const int o = obase + oi;
          const float b = (mode == 2) ? bF[o] : dec16(b16[o], mode);
          const float rr = v + b;
          const size_t idx = (size_t)n * O_TOT + o;
          if (mode == 0)      ((__hip_bfloat16*)outv)[idx] = __float2bfloat16(rr);
          else if (mode == 1) ((uint16_t*)outv)[idx] = f2h_bits(rr);
          else                ((float*)outv)[idx] = rr;
        }
      }
    }
    __syncthreads();
  }
}

extern "C" void kernel_launch(void* const* d_in, const int* in_sizes, int n_in,
                              void* d_out, int out_size, void* d_ws, size_t ws_size,
                              hipStream_t stream)
{
  const uint16_t* x       = (const uint16_t*)d_in[0];
  const uint32_t* qweight = (const uint32_t*)d_in[1];
  const uint32_t* qzeros  = (const uint32_t*)d_in[2];
  const uint16_t* scales  = (const uint16_t*)d_in[3];
  const uint16_t* bias    = (const uint16_t*)d_in[4];
  uint8_t* ws = (uint8_t*)d_ws;
  int* flag = (int*)d_ws;

  if (ws_size >= WS_NEED_V13) {
    hipLaunchKernelGGL(prep_fast_kernel, dim3(128), dim3(64), 0, stream, x, ws);
    hipLaunchKernelGGL(wq_mfma_fullk_kernel, dim3(448), dim3(256), 0, stream,
                       x, qweight, qzeros, scales, bias, d_out, ws);
  } else {
    hipLaunchKernelGGL(sniff_kernel, dim3(1), dim3(64), 0, stream, x, flag);
    hipLaunchKernelGGL(wq_fallback_kernel, dim3(NBLK), dim3(NTHR), 0, stream,
                       x, qweight, qzeros, scales, bias, d_out, flag);
  }
}

// Round 14
// 38.645 us; speedup vs baseline: 3.7813x; 3.7813x over previous
//
#include <hip/hip_runtime.h>
#include <hip/hip_bf16.h>
#include <stdint.h>

typedef short short8 __attribute__((ext_vector_type(8)));
typedef float f32x4  __attribute__((ext_vector_type(4)));

static constexpr int O_TOT = 28672;
static constexpr int K_TOT = 8192;
static constexpr int M_ROWS = 8;
static constexpr int KW = 1024;            // packed int32 words per output row

// workspace layout (R11-verified)
static constexpr size_t WS_X    = 4096;                           // 8 x 8192 bf16 = 128KB
static constexpr size_t WS_SG   = WS_X + (size_t)8 * K_TOT * 2;   // 64x8 f32 = 2KB
static constexpr size_t WS_PART = WS_SG + 64 * 8 * 4;             // f32 [64][28672] = 7.34MB
static constexpr size_t WS_NEED_V11 = WS_PART + (size_t)64 * O_TOT * 4 + 64;
static constexpr size_t WS_NEED_R7  = WS_SG + 64 * 8 * 4 + 64;

// mode: 0 = bf16, 1 = fp16, 2 = f32
__device__ __forceinline__ float dec16(uint16_t u, int mode) {
  if (mode == 0) {
    union { uint32_t i; float f; } v; v.i = ((uint32_t)u) << 16; return v.f;
  } else {
    union { uint16_t u; _Float16 h; } v; v.u = u; return (float)v.h;
  }
}
__device__ __forceinline__ uint16_t f2bf_bits(float f) {
  union { __hip_bfloat16 b; uint16_t u; } v; v.b = __float2bfloat16(f); return v.u;
}
__device__ __forceinline__ uint16_t f2h_bits(float f) {
  union { uint16_t u; _Float16 h; } v; v.h = (_Float16)f; return v.u;
}

// wave-level sniff of x[0..1023] (verified R3-R13); uniform across lanes
__device__ __forceinline__ int wave_sniff(const uint16_t* __restrict__ x) {
  const int t = threadIdx.x & 63;
  int ce = 0, co = 0;
  #pragma unroll
  for (int i = 0; i < 2; ++i) {
    const uint4 u = *reinterpret_cast<const uint4*>(x + (size_t)(t + 64 * i) * 8);
    const uint32_t d[4] = {u.x, u.y, u.z, u.w};
    #pragma unroll
    for (int j = 0; j < 4; ++j) {
      const int elo = (d[j] >> 7)  & 0xFF;
      const int ehi = (d[j] >> 23) & 0xFF;
      ce += (elo >= 118 && elo <= 131);
      co += (ehi >= 118 && ehi <= 131);
    }
  }
  for (int d = 32; d; d >>= 1) { ce += __shfl_xor(ce, d); co += __shfl_xor(co, d); }
  return (ce > 358 && co > 358) ? 0 : ((co > 358) ? 2 : 1);
}

// --- prep_fast: 128 blocks x 64 threads; sniff + decode/permute x + group sums
//     (shuffle-only; correctness-verified in R13's passing run) ---
__global__ __launch_bounds__(64)
void prep_fast_kernel(const uint16_t* __restrict__ x16, uint8_t* __restrict__ ws) {
  const int t = threadIdx.x;
  const int mode = wave_sniff(x16);
  if (blockIdx.x == 0 && t == 0) *reinterpret_cast<int*>(ws) = mode;

  const int tid = blockIdx.x * 64 + t;              // 8192 threads total
  const int r = tid >> 10, wb = tid & 1023;
  uint16_t s[8];
  if (mode == 2) {
    const float* xF = (const float*)x16;
    #pragma unroll
    for (int j = 0; j < 8; ++j) s[j] = f2bf_bits(xF[(size_t)r * K_TOT + wb * 8 + j]);
  } else {
    const uint4 u = *reinterpret_cast<const uint4*>(x16 + (size_t)r * K_TOT + wb * 8);
    const uint32_t d[4] = {u.x, u.y, u.z, u.w};
    #pragma unroll
    for (int j = 0; j < 8; ++j) {
      const uint16_t raw = (j & 1) ? (uint16_t)(d[j >> 1] >> 16) : (uint16_t)(d[j >> 1] & 0xffffu);
      s[j] = (mode == 0) ? raw : f2bf_bits(dec16(raw, 1));
    }
  }
  uint16_t p[8];
  p[0] = s[0]; p[1] = s[4]; p[2] = s[1]; p[3] = s[5];
  p[4] = s[2]; p[5] = s[6]; p[6] = s[3]; p[7] = s[7];
  uint4 o;
  o.x = (uint32_t)p[0] | ((uint32_t)p[1] << 16);
  o.y = (uint32_t)p[2] | ((uint32_t)p[3] << 16);
  o.z = (uint32_t)p[4] | ((uint32_t)p[5] << 16);
  o.w = (uint32_t)p[6] | ((uint32_t)p[7] << 16);
  *reinterpret_cast<uint4*>((uint16_t*)(ws + WS_X) + (size_t)r * K_TOT + wb * 8) = o;

  // group sum: 16 consecutive threads = one (group, row); butterfly shuffle
  float loc = 0.f;
  #pragma unroll
  for (int j = 0; j < 8; ++j) loc += dec16(p[j], 0);
  loc += __shfl_xor(loc, 1);
  loc += __shfl_xor(loc, 2);
  loc += __shfl_xor(loc, 4);
  loc += __shfl_xor(loc, 8);
  if ((t & 15) == 0) {
    const int G = wb >> 4;
    ((float*)(ws + WS_SG))[G * 8 + r] = loc;
  }
}

// --- v11 main (VERBATIM from R11's 38.6us run): issue-early q loads, LDS x-chunk,
//     direct scale loads, partials to ws. NO fence, NO atomics. ---
__global__ __launch_bounds__(256)
void wq_mfma5_kernel(const uint32_t* __restrict__ qweight,
                     const uint32_t* __restrict__ qzeros,
                     const uint16_t* __restrict__ sc16,
                     const uint8_t* __restrict__ ws,
                     float* __restrict__ part,
                     const int* __restrict__ flag)
{
  __shared__ __align__(16) uint4 xl[8 * 129];   // 16.5KB
  __shared__ float sgl[64];
  const int mode = *flag;
  const int t = threadIdx.x, wid = t >> 6, lane = t & 63;
  const int c = lane & 15, g4 = lane >> 4;
  const int bi = blockIdx.x;
  const int ct = bi >> 3, kq = bi & 7;          // kq fast: streaming sweep
  const int cg = ct * 64 + wid * 16 + c;

  // issue ALL 8 qweight loads FIRST: latency hides under x staging + barrier
  const uint32_t* qp = qweight + (size_t)cg * KW + kq * 128;
  uint4 q[8];
  #pragma unroll
  for (int T = 0; T < 8; ++T)
    q[T] = *reinterpret_cast<const uint4*>(qp + 16 * T + 4 * g4);

  const uint32_t qzw = qzeros[cg * 8 + kq];     // 8 zeros of this chunk
  float sv[8];
  if (mode == 2) {
    const float* sp = (const float*)sc16 + (size_t)cg * 64 + kq * 8;
    const f32x4 s0 = *reinterpret_cast<const f32x4*>(sp);
    const f32x4 s1 = *reinterpret_cast<const f32x4*>(sp + 4);
    sv[0] = s0[0]; sv[1] = s0[1]; sv[2] = s0[2]; sv[3] = s0[3];
    sv[4] = s1[0]; sv[5] = s1[1]; sv[6] = s1[2]; sv[7] = s1[3];
  } else {
    const uint4 sr = *reinterpret_cast<const uint4*>(sc16 + (size_t)cg * 64 + kq * 8);
    const uint32_t sd[4] = {sr.x, sr.y, sr.z, sr.w};
    #pragma unroll
    for (int j = 0; j < 4; ++j) {
      sv[2*j]   = dec16((uint16_t)(sd[j] & 0xffffu), mode);
      sv[2*j+1] = dec16((uint16_t)(sd[j] >> 16), mode);
    }
  }

  // stage x chunk (1024 uint4) + group sums
  {
    const uint4* src = (const uint4*)(ws + WS_X);
    #pragma unroll
    for (int j = 0; j < 4; ++j) {
      const int idx = j * 256 + t;
      const int r = idx >> 7, w = idx & 127;
      xl[r * 129 + w] = src[(size_t)r * 1024 + kq * 128 + w];
    }
    if (t < 64) sgl[t] = ((const float*)(ws + WS_SG))[kq * 64 + t];
  }
  __syncthreads();

  f32x4 D = {0.f, 0.f, 0.f, 0.f};
  #pragma unroll
  for (int T = 0; T < 8; ++T) {
    const uint4 a0 = xl[(c & 7) * 129 + 16 * T + 4 * g4 + 0];
    const uint4 a1 = xl[(c & 7) * 129 + 16 * T + 4 * g4 + 1];
    const uint4 a2 = xl[(c & 7) * 129 + 16 * T + 4 * g4 + 2];
    const uint4 a3 = xl[(c & 7) * 129 + 16 * T + 4 * g4 + 3];
    const f32x4 sgv = *reinterpret_cast<const f32x4*>(&sgl[T * 8 + (g4 & 1) * 4]);

    f32x4 tmp = {0.f, 0.f, 0.f, 0.f};
    const uint32_t wvv[4] = {q[T].x, q[T].y, q[T].z, q[T].w};
    const uint4   av[4] = {a0, a1, a2, a3};
    #pragma unroll
    for (int u = 0; u < 4; ++u) {
      union { uint32_t d[4]; short8 s; } bb;
      bb.d[0] = ( wvv[u]        & 0x000F000Fu) | 0x43004300u;
      bb.d[1] = ((wvv[u] >> 4)  & 0x000F000Fu) | 0x43004300u;
      bb.d[2] = ((wvv[u] >> 8)  & 0x000F000Fu) | 0x43004300u;
      bb.d[3] = ((wvv[u] >> 12) & 0x000F000Fu) | 0x43004300u;
      union { uint4 q; short8 s; } aa; aa.q = av[u];
      tmp = __builtin_amdgcn_mfma_f32_16x16x32_bf16(aa.s, bb.s, tmp, 0, 0, 0);
    }
    const float zf = (float)((qzw >> (T * 4)) & 15u);
    const float c128z = 128.0f + zf;
    D[0] += sv[T] * (tmp[0] - c128z * sgv[0]);
    D[1] += sv[T] * (tmp[1] - c128z * sgv[1]);
    D[2] += sv[T] * (tmp[2] - c128z * sgv[2]);
    D[3] += sv[T] * (tmp[3] - c128z * sgv[3]);
  }

  if (g4 < 2) {
    #pragma unroll
    for (int reg = 0; reg < 4; ++reg) {
      const int r = g4 * 4 + reg;               // D row = (lane>>4)*4 + reg (m89)
      part[((size_t)kq * 8 + r) * O_TOT + cg] = D[reg];
    }
  }
}

// --- reduce: sum 8 k-chunk partials + bias -> output (VERBATIM R9/R11-verified) ---
__global__ __launch_bounds__(256)
void reduce_kernel(const float* __restrict__ part,
                   const uint16_t* __restrict__ b16,
                   void* __restrict__ outv,
                   const int* __restrict__ flag)
{
  const int mode = *flag;
  const int idx = blockIdx.x * 256 + threadIdx.x;  // 224 blocks: 57344 threads
  const int lin = idx * 4;
  const int r = lin / O_TOT, o = lin - r * O_TOT;
  f32x4 s = {0.f, 0.f, 0.f, 0.f};
  #pragma unroll
  for (int k = 0; k < 8; ++k) {
    const f32x4 p = *reinterpret_cast<const f32x4*>(part + ((size_t)k * 8 + r) * O_TOT + o);
    s[0] += p[0]; s[1] += p[1]; s[2] += p[2]; s[3] += p[3];
  }
  if (mode == 2) {
    const float* bF = (const float*)b16;
    const f32x4 b = *reinterpret_cast<const f32x4*>(bF + o);
    f32x4 w = {s[0] + b[0], s[1] + b[1], s[2] + b[2], s[3] + b[3]};
    *reinterpret_cast<f32x4*>((float*)outv + (size_t)r * O_TOT + o) = w;
  } else {
    const uint2 bb = *reinterpret_cast<const uint2*>(b16 + o);
    const uint16_t bu[4] = {(uint16_t)(bb.x & 0xffffu), (uint16_t)(bb.x >> 16),
                            (uint16_t)(bb.y & 0xffffu), (uint16_t)(bb.y >> 16)};
    uint16_t w[4];
    #pragma unroll
    for (int j = 0; j < 4; ++j) {
      const float v = s[j] + dec16(bu[j], mode);
      w[j] = (mode == 0) ? f2bf_bits(v) : f2h_bits(v);
    }
    uint2 pk;
    pk.x = (uint32_t)w[0] | ((uint32_t)w[1] << 16);
    pk.y = (uint32_t)w[2] | ((uint32_t)w[3] << 16);
    *reinterpret_cast<uint2*>((uint16_t*)outv + (size_t)r * O_TOT + o) = pk;
  }
}

// ============ fallback tiers (verified earlier rounds) ============

__global__ void sniff_kernel(const uint16_t* __restrict__ x, int* __restrict__ flag) {
  const int mode = wave_sniff(x);
  if (threadIdx.x == 0) *flag = mode;
}

// R7-tier main (verified) for mid-size ws
__global__ __launch_bounds__(256)
void wq_mfma_kernel(const uint32_t* __restrict__ qweight,
                    const uint32_t* __restrict__ qzeros,
                    const uint16_t* __restrict__ sc16,
                    const uint16_t* __restrict__ b16,
                    void* __restrict__ outv,
                    const uint8_t* __restrict__ ws,
                    const int* __restrict__ flag)
{
  __shared__ float red[4][64][4];
  const int mode = *flag;
  const float* scF = (const float*)sc16;
  const float* bF  = (const float*)b16;
  const int t = threadIdx.x, wid = t >> 6, lane = t & 63;
  const int c = lane & 15, g4 = lane >> 4;
  const int cg = blockIdx.x * 16 + c;

  const uint16_t* xb  = (const uint16_t*)(ws + WS_X);
  const float*    sgp = (const float*)(ws + WS_SG);
  const uint32_t* qp  = qweight + (size_t)cg * KW;
  const uint4*  abase = (const uint4*)(xb + (size_t)(c & 7) * K_TOT);
  const int G0   = wid * 16;
  const int boff = 4 * g4;
  const uint2 qz = *reinterpret_cast<const uint2*>(qzeros + cg * 8 + wid * 2);

  f32x4 D = {0.f, 0.f, 0.f, 0.f};
  uint4 q0 = *reinterpret_cast<const uint4*>(qp + 16 * G0 + boff);
  uint4 a0[4], a1[4]; uint4 q1;
  #pragma unroll
  for (int u = 0; u < 4; ++u) a0[u] = abase[16 * G0 + boff + u];

#define GBODY(TT, QC, AC, QN, AN)                                              \
  do {                                                                         \
    const int Gc = G0 + (TT);                                                  \
    const int Gn = (Gc + 1 <= 63) ? Gc + 1 : 63;                               \
    QN = *reinterpret_cast<const uint4*>(qp + 16 * Gn + boff);                 \
    AN[0] = abase[16 * Gn + boff + 0];                                         \
    AN[1] = abase[16 * Gn + boff + 1];                                         \
    AN[2] = abase[16 * Gn + boff + 2];                                         \
    AN[3] = abase[16 * Gn + boff + 3];                                         \
    f32x4 tmp = {0.f, 0.f, 0.f, 0.f};                                          \
    const uint32_t wvv[4] = {QC.x, QC.y, QC.z, QC.w};                          \
    _Pragma("unroll")                                                          \
    for (int u = 0; u < 4; ++u) {                                              \
      union { uint32_t d[4]; short8 s; } bb;                                   \
      bb.d[0] = ( wvv[u]        & 0x000F000Fu) | 0x43004300u;                  \
      bb.d[1] = ((wvv[u] >> 4)  & 0x000F000Fu) | 0x43004300u;                  \
      bb.d[2] = ((wvv[u] >> 8)  & 0x000F000Fu) | 0x43004300u;                  \
      bb.d[3] = ((wvv[u] >> 12) & 0x000F000Fu) | 0x43004300u;                  \
      union { uint4 q; short8 s; } aa; aa.q = AC[u];                           \
      tmp = __builtin_amdgcn_mfma_f32_16x16x32_bf16(aa.s, bb.s, tmp, 0, 0, 0); \
    }                                                                          \
    const uint32_t zraw = ((TT) < 8) ? qz.x : qz.y;                            \
    const float zf = (float)((zraw >> (((TT) & 7) * 4)) & 15u);                \
    const float sv2 = (mode == 2) ? scF[cg * 64 + Gc]                          \
                                  : dec16(sc16[cg * 64 + Gc], mode);           \
    const f32x4 sgv = *reinterpret_cast<const f32x4*>(sgp + Gc * 8 + (g4 & 1) * 4); \
    const float c128z = 128.0f + zf;                                           \
    D[0] += sv2 * (tmp[0] - c128z * sgv[0]);                                   \
    D[1] += sv2 * (tmp[1] - c128z * sgv[1]);                                   \
    D[2] += sv2 * (tmp[2] - c128z * sgv[2]);                                   \
    D[3] += sv2 * (tmp[3] - c128z * sgv[3]);                                   \
  } while (0)

  for (int T = 0; T < 16; T += 2) {
    GBODY(T,     q0, a0, q1, a1);
    GBODY(T + 1, q1, a1, q0, a0);
  }
#undef GBODY

  *reinterpret_cast<f32x4*>(&red[wid][lane][0]) = D;
  __syncthreads();

  if (t < 128) {
    const int r = t >> 4, cc = t & 15;
    const int ln = (r >> 2) * 16 + cc, rg = r & 3;
    float v = red[0][ln][rg] + red[1][ln][rg] + red[2][ln][rg] + red[3][ln][rg];
    const int o = blockIdx.x * 16 + cc;
    v += (mode == 2) ? bF[o] : dec16(b16[o], mode);
    const size_t idx = (size_t)r * O_TOT + o;
    if (mode == 0)      ((__hip_bfloat16*)outv)[idx] = __float2bfloat16(v);
    else if (mode == 1) ((uint16_t*)outv)[idx] = f2h_bits(v);
    else                ((float*)outv)[idx] = v;
  }
}

static constexpr int NTHR = 512, O_PER_IT = 2, ITERS = 14, NBLK = 1024;
__global__ __launch_bounds__(NTHR, 1)
void wq_fallback_kernel(const uint16_t* __restrict__ x16,
                        const uint32_t* __restrict__ qweight,
                        const uint32_t* __restrict__ qzeros,
                        const uint16_t* __restrict__ sc16,
                        const uint16_t* __restrict__ b16,
                        void* __restrict__ outv,
                        const int* __restrict__ flag)
{
  __shared__ float lds[O_PER_IT][M_ROWS][NTHR];
  const int mode = *flag;
  const int t = threadIdx.x;
  const float* xF  = (const float*)x16;
  const float* scF = (const float*)sc16;
  const float* bF  = (const float*)b16;
  float xf[M_ROWS][16];
  {
    const int kbase = 16 * t;
    if (mode == 2) {
      #pragma unroll
      for (int n = 0; n < M_ROWS; ++n)
        #pragma unroll
        for (int i = 0; i < 16; ++i) xf[n][i] = xF[(size_t)n * K_TOT + kbase + i];
    } else {
      #pragma unroll
      for (int n = 0; n < M_ROWS; ++n)
        #pragma unroll
        for (int i = 0; i < 16; ++i) xf[n][i] = dec16(x16[(size_t)n * K_TOT + kbase + i], mode);
    }
  }
  const int g = t >> 3, zsh = (g & 7) * 4, zword = g >> 3;
  for (int it = 0; it < ITERS; ++it) {
    const int obase = blockIdx.x * (ITERS * O_PER_IT) + it * O_PER_IT;
    #pragma unroll
    for (int oi = 0; oi < O_PER_IT; ++oi) {
      const int o = obase + oi;
      const uint32_t zw = qzeros[o * 8 + zword];
      const float z = (float)((zw >> zsh) & 15u);
      const float s = (mode == 2) ? scF[o * 64 + g] : dec16(sc16[o * 64 + g], mode);
      const uint32_t w0 = qweight[(size_t)o * KW + 2 * t];
      const uint32_t w1 = qweight[(size_t)o * KW + 2 * t + 1];
      float d[M_ROWS];
      #pragma unroll
      for (int n = 0; n < M_ROWS; ++n) d[n] = 0.f;
      const uint32_t wvv[2] = { w0, w1 };
      #pragma unroll
      for (int w = 0; w < 2; ++w)
        #pragma unroll
        for (int j = 0; j < 8; ++j) {
          const float q = (float)((wvv[w] >> (4 * j)) & 15u);
          const float wgt = s * (q - z);
          #pragma unroll
          for (int n = 0; n < M_ROWS; ++n) d[n] = fmaf(wgt, xf[n][8 * w + j], d[n]);
        }
      #pragma unroll
      for (int n = 0; n < M_ROWS; ++n) lds[oi][n][t] = d[n];
    }
    __syncthreads();
    {
      const int wvid = t >> 6, lanei = t & 63;
      #pragma unroll
      for (int cc2 = 0; cc2 < 2; ++cc2) {
        const int p = 2 * wvid + cc2, oi = p >> 3, n = p & 7;
        float v = 0.f;
        #pragma unroll
        for (int i = 0; i < 8; ++i) v += lds[oi][n][lanei + 64 * i];
        v += __shfl_xor(v, 32); v += __shfl_xor(v, 16); v += __shfl_xor(v, 8);
        v += __shfl_xor(v, 4);  v += __shfl_xor(v, 2);  v += __shfl_xor(v, 1);
        if (lanei == 0) {
          const int o = obase + oi;
          const float b = (mode == 2) ? bF[o] : dec16(b16[o], mode);
          const float rr = v + b;
          const size_t idx = (size_t)n * O_TOT + o;
          if (mode == 0)      ((__hip_bfloat16*)outv)[idx] = __float2bfloat16(rr);
          else if (mode == 1) ((uint16_t*)outv)[idx] = f2h_bits(rr);
          else                ((float*)outv)[idx] = rr;
        }
      }
    }
    __syncthreads();
  }
}

extern "C" void kernel_launch(void* const* d_in, const int* in_sizes, int n_in,
                              void* d_out, int out_size, void* d_ws, size_t ws_size,
                              hipStream_t stream)
{
  const uint16_t* x       = (const uint16_t*)d_in[0];
  const uint32_t* qweight = (const uint32_t*)d_in[1];
  const uint32_t* qzeros  = (const uint32_t*)d_in[2];
  const uint16_t* scales  = (const uint16_t*)d_in[3];
  const uint16_t* bias    = (const uint16_t*)d_in[4];
  uint8_t* ws = (uint8_t*)d_ws;
  int* flag = (int*)d_ws;

  if (ws_size >= WS_NEED_V11) {
    float* part = (float*)(ws + WS_PART);
    hipLaunchKernelGGL(prep_fast_kernel, dim3(128), dim3(64), 0, stream, x, ws);
    hipLaunchKernelGGL(wq_mfma5_kernel, dim3(3584), dim3(256), 0, stream,
                       qweight, qzeros, scales, ws, part, flag);
    hipLaunchKernelGGL(reduce_kernel, dim3(224), dim3(256), 0, stream,
                       part, bias, d_out, flag);
  } else if (ws_size >= WS_NEED_R7) {
    hipLaunchKernelGGL(prep_fast_kernel, dim3(128), dim3(64), 0, stream, x, ws);
    hipLaunchKernelGGL(wq_mfma_kernel, dim3(1792), dim3(256), 0, stream,
                       qweight, qzeros, scales, bias, d_out, ws, flag);
  } else {
    hipLaunchKernelGGL(sniff_kernel, dim3(1), dim3(64), 0, stream, x, flag);
    hipLaunchKernelGGL(wq_fallback_kernel, dim3(NBLK), dim3(NTHR), 0, stream,
                       x, qweight, qzeros, scales, bias, d_out, flag);
  }
}

// Round 15
// 38.407 us; speedup vs baseline: 3.8046x; 1.0062x over previous
//
#include <hip/hip_runtime.h>
#include <hip/hip_bf16.h>
#include <stdint.h>

typedef short short8 __attribute__((ext_vector_type(8)));
typedef float f32x4  __attribute__((ext_vector_type(4)));

static constexpr int O_TOT = 28672;
static constexpr int K_TOT = 8192;
static constexpr int M_ROWS = 8;
static constexpr int KW = 1024;            // packed int32 words per output row

// workspace layout (R11/R14-verified)
static constexpr size_t WS_X    = 4096;                           // 8 x 8192 bf16 = 128KB
static constexpr size_t WS_SG   = WS_X + (size_t)8 * K_TOT * 2;   // 64x8 f32 = 2KB
static constexpr size_t WS_PART = WS_SG + 64 * 8 * 4;             // f32 [64][28672] = 7.34MB
static constexpr size_t WS_NEED_V11 = WS_PART + (size_t)64 * O_TOT * 4 + 64;
static constexpr size_t WS_NEED_R7  = WS_SG + 64 * 8 * 4 + 64;

// mode: 0 = bf16, 1 = fp16, 2 = f32
__device__ __forceinline__ float dec16(uint16_t u, int mode) {
  if (mode == 0) {
    union { uint32_t i; float f; } v; v.i = ((uint32_t)u) << 16; return v.f;
  } else {
    union { uint16_t u; _Float16 h; } v; v.u = u; return (float)v.h;
  }
}
__device__ __forceinline__ uint16_t f2bf_bits(float f) {
  union { __hip_bfloat16 b; uint16_t u; } v; v.b = __float2bfloat16(f); return v.u;
}
__device__ __forceinline__ uint16_t f2h_bits(float f) {
  union { uint16_t u; _Float16 h; } v; v.h = (_Float16)f; return v.u;
}

// wave-level sniff of x[0..1023] (verified R3-R14); uniform across lanes
__device__ __forceinline__ int wave_sniff(const uint16_t* __restrict__ x) {
  const int t = threadIdx.x & 63;
  int ce = 0, co = 0;
  #pragma unroll
  for (int i = 0; i < 2; ++i) {
    const uint4 u = *reinterpret_cast<const uint4*>(x + (size_t)(t + 64 * i) * 8);
    const uint32_t d[4] = {u.x, u.y, u.z, u.w};
    #pragma unroll
    for (int j = 0; j < 4; ++j) {
      const int elo = (d[j] >> 7)  & 0xFF;
      const int ehi = (d[j] >> 23) & 0xFF;
      ce += (elo >= 118 && elo <= 131);
      co += (ehi >= 118 && ehi <= 131);
    }
  }
  for (int d = 32; d; d >>= 1) { ce += __shfl_xor(ce, d); co += __shfl_xor(co, d); }
  return (ce > 358 && co > 358) ? 0 : ((co > 358) ? 2 : 1);
}

// --- prep_fast: 128 blocks x 64 threads (verified R13/R14) ---
__global__ __launch_bounds__(64)
void prep_fast_kernel(const uint16_t* __restrict__ x16, uint8_t* __restrict__ ws) {
  const int t = threadIdx.x;
  const int mode = wave_sniff(x16);
  if (blockIdx.x == 0 && t == 0) *reinterpret_cast<int*>(ws) = mode;

  const int tid = blockIdx.x * 64 + t;              // 8192 threads total
  const int r = tid >> 10, wb = tid & 1023;
  uint16_t s[8];
  if (mode == 2) {
    const float* xF = (const float*)x16;
    #pragma unroll
    for (int j = 0; j < 8; ++j) s[j] = f2bf_bits(xF[(size_t)r * K_TOT + wb * 8 + j]);
  } else {
    const uint4 u = *reinterpret_cast<const uint4*>(x16 + (size_t)r * K_TOT + wb * 8);
    const uint32_t d[4] = {u.x, u.y, u.z, u.w};
    #pragma unroll
    for (int j = 0; j < 8; ++j) {
      const uint16_t raw = (j & 1) ? (uint16_t)(d[j >> 1] >> 16) : (uint16_t)(d[j >> 1] & 0xffffu);
      s[j] = (mode == 0) ? raw : f2bf_bits(dec16(raw, 1));
    }
  }
  uint16_t p[8];
  p[0] = s[0]; p[1] = s[4]; p[2] = s[1]; p[3] = s[5];
  p[4] = s[2]; p[5] = s[6]; p[6] = s[3]; p[7] = s[7];
  uint4 o;
  o.x = (uint32_t)p[0] | ((uint32_t)p[1] << 16);
  o.y = (uint32_t)p[2] | ((uint32_t)p[3] << 16);
  o.z = (uint32_t)p[4] | ((uint32_t)p[5] << 16);
  o.w = (uint32_t)p[6] | ((uint32_t)p[7] << 16);
  *reinterpret_cast<uint4*>((uint16_t*)(ws + WS_X) + (size_t)r * K_TOT + wb * 8) = o;

  float loc = 0.f;
  #pragma unroll
  for (int j = 0; j < 8; ++j) loc += dec16(p[j], 0);
  loc += __shfl_xor(loc, 1);
  loc += __shfl_xor(loc, 2);
  loc += __shfl_xor(loc, 4);
  loc += __shfl_xor(loc, 8);
  if ((t & 15) == 0) {
    const int G = wb >> 4;
    ((float*)(ws + WS_SG))[G * 8 + r] = loc;
  }
}

// --- v15 main: qweight routed through LDS with COALESCED loads
//     (2 rows x 512B contiguous per wave-instruction vs 16x64B scatter).
//     q-LDS padded to 132 dw/row -> B-reads conflict-free ((c+g4)%8 uniform). ---
__global__ __launch_bounds__(256)
void wq_mfma7_kernel(const uint32_t* __restrict__ qweight,
                     const uint32_t* __restrict__ qzeros,
                     const uint16_t* __restrict__ sc16,
                     const uint8_t* __restrict__ ws,
                     float* __restrict__ part,
                     const int* __restrict__ flag)
{
  __shared__ __align__(16) uint32_t ql[64 * 132];   // 33.8KB padded q tile
  __shared__ __align__(16) uint4 xl[8 * 129];       // 16.5KB x tile
  __shared__ float sgl[64];
  const int mode = *flag;
  const int t = threadIdx.x, wid = t >> 6, lane = t & 63;
  const int c = lane & 15, g4 = lane >> 4;
  const int bi = blockIdx.x;
  const int ct = bi >> 3, kq = bi & 7;              // kq fast: streaming sweep
  const int cg = ct * 64 + wid * 16 + c;

  // 1. coalesced q loads FIRST: pass p -> 8 rows x 512B; wave = 2 rows contiguous
  uint4 qr[8];
  {
    const uint32_t* qbase = qweight + (size_t)(ct * 64) * KW + kq * 128;
    #pragma unroll
    for (int p = 0; p < 8; ++p) {
      const int idx = p * 256 + t;
      const int row = idx >> 5, col = idx & 31;
      qr[p] = *reinterpret_cast<const uint4*>(qbase + (size_t)row * KW + col * 4);
    }
  }
  // 2. x stage loads (L2-hot)
  uint4 xr[4];
  {
    const uint4* src = (const uint4*)(ws + WS_X);
    #pragma unroll
    for (int j = 0; j < 4; ++j) {
      const int idx = j * 256 + t;
      const int r = idx >> 7, w = idx & 127;
      xr[j] = src[(size_t)r * 1024 + kq * 128 + w];
    }
  }
  const float sg0 = (t < 64) ? ((const float*)(ws + WS_SG))[kq * 64 + t] : 0.f;

  // 3. metadata (verified R11 pattern)
  const uint32_t qzw = qzeros[cg * 8 + kq];
  float sv[8];
  if (mode == 2) {
    const float* sp = (const float*)sc16 + (size_t)cg * 64 + kq * 8;
    const f32x4 s0 = *reinterpret_cast<const f32x4*>(sp);
    const f32x4 s1 = *reinterpret_cast<const f32x4*>(sp + 4);
    sv[0] = s0[0]; sv[1] = s0[1]; sv[2] = s0[2]; sv[3] = s0[3];
    sv[4] = s1[0]; sv[5] = s1[1]; sv[6] = s1[2]; sv[7] = s1[3];
  } else {
    const uint4 sr = *reinterpret_cast<const uint4*>(sc16 + (size_t)cg * 64 + kq * 8);
    const uint32_t sd[4] = {sr.x, sr.y, sr.z, sr.w};
    #pragma unroll
    for (int j = 0; j < 4; ++j) {
      sv[2*j]   = dec16((uint16_t)(sd[j] & 0xffffu), mode);
      sv[2*j+1] = dec16((uint16_t)(sd[j] >> 16), mode);
    }
  }

  // 4. LDS writes + barrier
  #pragma unroll
  for (int p = 0; p < 8; ++p) {
    const int idx = p * 256 + t;
    const int row = idx >> 5, col = idx & 31;
    *reinterpret_cast<uint4*>(&ql[row * 132 + col * 4]) = qr[p];
  }
  #pragma unroll
  for (int j = 0; j < 4; ++j) {
    const int idx = j * 256 + t;
    const int r = idx >> 7, w = idx & 127;
    xl[r * 129 + w] = xr[j];
  }
  if (t < 64) sgl[t] = sg0;
  __syncthreads();

  // 5. MFMA loop: B-words from q-LDS (1 ds_read_b128 per T), A from x-LDS
  const int qrow = wid * 16 + c;
  f32x4 D = {0.f, 0.f, 0.f, 0.f};
  #pragma unroll
  for (int T = 0; T < 8; ++T) {
    const uint4 bq = *reinterpret_cast<const uint4*>(&ql[qrow * 132 + 16 * T + 4 * g4]);
    const uint4 a0 = xl[(c & 7) * 129 + 16 * T + 4 * g4 + 0];
    const uint4 a1 = xl[(c & 7) * 129 + 16 * T + 4 * g4 + 1];
    const uint4 a2 = xl[(c & 7) * 129 + 16 * T + 4 * g4 + 2];
    const uint4 a3 = xl[(c & 7) * 129 + 16 * T + 4 * g4 + 3];
    const f32x4 sgv = *reinterpret_cast<const f32x4*>(&sgl[T * 8 + (g4 & 1) * 4]);

    f32x4 tmp = {0.f, 0.f, 0.f, 0.f};
    const uint32_t wvv[4] = {bq.x, bq.y, bq.z, bq.w};
    const uint4   av[4] = {a0, a1, a2, a3};
    #pragma unroll
    for (int u = 0; u < 4; ++u) {
      union { uint32_t d[4]; short8 s; } bb;
      bb.d[0] = ( wvv[u]        & 0x000F000Fu) | 0x43004300u;
      bb.d[1] = ((wvv[u] >> 4)  & 0x000F000Fu) | 0x43004300u;
      bb.d[2] = ((wvv[u] >> 8)  & 0x000F000Fu) | 0x43004300u;
      bb.d[3] = ((wvv[u] >> 12) & 0x000F000Fu) | 0x43004300u;
      union { uint4 q; short8 s; } aa; aa.q = av[u];
      tmp = __builtin_amdgcn_mfma_f32_16x16x32_bf16(aa.s, bb.s, tmp, 0, 0, 0);
    }
    const float zf = (float)((qzw >> (T * 4)) & 15u);
    const float c128z = 128.0f + zf;
    D[0] += sv[T] * (tmp[0] - c128z * sgv[0]);
    D[1] += sv[T] * (tmp[1] - c128z * sgv[1]);
    D[2] += sv[T] * (tmp[2] - c128z * sgv[2]);
    D[3] += sv[T] * (tmp[3] - c128z * sgv[3]);
  }

  if (g4 < 2) {
    #pragma unroll
    for (int reg = 0; reg < 4; ++reg) {
      const int r = g4 * 4 + reg;               // D row = (lane>>4)*4 + reg (m89)
      part[((size_t)kq * 8 + r) * O_TOT + cg] = D[reg];
    }
  }
}

// --- reduce: sum 8 k-chunk partials + bias -> output (VERBATIM R9/R11/R14-verified) ---
__global__ __launch_bounds__(256)
void reduce_kernel(const float* __restrict__ part,
                   const uint16_t* __restrict__ b16,
                   void* __restrict__ outv,
                   const int* __restrict__ flag)
{
  const int mode = *flag;
  const int idx = blockIdx.x * 256 + threadIdx.x;  // 224 blocks: 57344 threads
  const int lin = idx * 4;
  const int r = lin / O_TOT, o = lin - r * O_TOT;
  f32x4 s = {0.f, 0.f, 0.f, 0.f};
  #pragma unroll
  for (int k = 0; k < 8; ++k) {
    const f32x4 p = *reinterpret_cast<const f32x4*>(part + ((size_t)k * 8 + r) * O_TOT + o);
    s[0] += p[0]; s[1] += p[1]; s[2] += p[2]; s[3] += p[3];
  }
  if (mode == 2) {
    const float* bF = (const float*)b16;
    const f32x4 b = *reinterpret_cast<const f32x4*>(bF + o);
    f32x4 w = {s[0] + b[0], s[1] + b[1], s[2] + b[2], s[3] + b[3]};
    *reinterpret_cast<f32x4*>((float*)outv + (size_t)r * O_TOT + o) = w;
  } else {
    const uint2 bb = *reinterpret_cast<const uint2*>(b16 + o);
    const uint16_t bu[4] = {(uint16_t)(bb.x & 0xffffu), (uint16_t)(bb.x >> 16),
                            (uint16_t)(bb.y & 0xffffu), (uint16_t)(bb.y >> 16)};
    uint16_t w[4];
    #pragma unroll
    for (int j = 0; j < 4; ++j) {
      const float v = s[j] + dec16(bu[j], mode);
      w[j] = (mode == 0) ? f2bf_bits(v) : f2h_bits(v);
    }
    uint2 pk;
    pk.x = (uint32_t)w[0] | ((uint32_t)w[1] << 16);
    pk.y = (uint32_t)w[2] | ((uint32_t)w[3] << 16);
    *reinterpret_cast<uint2*>((uint16_t*)outv + (size_t)r * O_TOT + o) = pk;
  }
}

// ============ fallback tiers (verified earlier rounds) ============

__global__ void sniff_kernel(const uint16_t* __restrict__ x, int* __restrict__ flag) {
  const int mode = wave_sniff(x);
  if (threadIdx.x == 0) *flag = mode;
}

// R7-tier main (verified) for mid-size ws
__global__ __launch_bounds__(256)
void wq_mfma_kernel(const uint32_t* __restrict__ qweight,
                    const uint32_t* __restrict__ qzeros,
                    const uint16_t* __restrict__ sc16,
                    const uint16_t* __restrict__ b16,
                    void* __restrict__ outv,
                    const uint8_t* __restrict__ ws,
                    const int* __restrict__ flag)
{
  __shared__ float red[4][64][4];
  const int mode = *flag;
  const float* scF = (const float*)sc16;
  const float* bF  = (const float*)b16;
  const int t = threadIdx.x, wid = t >> 6, lane = t & 63;
  const int c = lane & 15, g4 = lane >> 4;
  const int cg = blockIdx.x * 16 + c;

  const uint16_t* xb  = (const uint16_t*)(ws + WS_X);
  const float*    sgp = (const float*)(ws + WS_SG);
  const uint32_t* qp  = qweight + (size_t)cg * KW;
  const uint4*  abase = (const uint4*)(xb + (size_t)(c & 7) * K_TOT);
  const int G0   = wid * 16;
  const int boff = 4 * g4;
  const uint2 qz = *reinterpret_cast<const uint2*>(qzeros + cg * 8 + wid * 2);

  f32x4 D = {0.f, 0.f, 0.f, 0.f};
  uint4 q0 = *reinterpret_cast<const uint4*>(qp + 16 * G0 + boff);
  uint4 a0[4], a1[4]; uint4 q1;
  #pragma unroll
  for (int u = 0; u < 4; ++u) a0[u] = abase[16 * G0 + boff + u];

#define GBODY(TT, QC, AC, QN, AN)                                              \
  do {                                                                         \
    const int Gc = G0 + (TT);                                                  \
    const int Gn = (Gc + 1 <= 63) ? Gc + 1 : 63;                               \
    QN = *reinterpret_cast<const uint4*>(qp + 16 * Gn + boff);                 \
    AN[0] = abase[16 * Gn + boff + 0];                                         \
    AN[1] = abase[16 * Gn + boff + 1];                                         \
    AN[2] = abase[16 * Gn + boff + 2];                                         \
    AN[3] = abase[16 * Gn + boff + 3];                                         \
    f32x4 tmp = {0.f, 0.f, 0.f, 0.f};                                          \
    const uint32_t wvv[4] = {QC.x, QC.y, QC.z, QC.w};                          \
    _Pragma("unroll")                                                          \
    for (int u = 0; u < 4; ++u) {                                              \
      union { uint32_t d[4]; short8 s; } bb;                                   \
      bb.d[0] = ( wvv[u]        & 0x000F000Fu) | 0x43004300u;                  \
      bb.d[1] = ((wvv[u] >> 4)  & 0x000F000Fu) | 0x43004300u;                  \
      bb.d[2] = ((wvv[u] >> 8)  & 0x000F000Fu) | 0x43004300u;                  \
      bb.d[3] = ((wvv[u] >> 12) & 0x000F000Fu) | 0x43004300u;                  \
      union { uint4 q; short8 s; } aa; aa.q = AC[u];                           \
      tmp = __builtin_amdgcn_mfma_f32_16x16x32_bf16(aa.s, bb.s, tmp, 0, 0, 0); \
    }                                                                          \
    const uint32_t zraw = ((TT) < 8) ? qz.x : qz.y;                            \
    const float zf = (float)((zraw >> (((TT) & 7) * 4)) & 15u);                \
    const float sv2 = (mode == 2) ? scF[cg * 64 + Gc]                          \
                                  : dec16(sc16[cg * 64 + Gc], mode);           \
    const f32x4 sgv = *reinterpret_cast<const f32x4*>(sgp + Gc * 8 + (g4 & 1) * 4); \
    const float c128z = 128.0f + zf;                                           \
    D[0] += sv2 * (tmp[0] - c128z * sgv[0]);                                   \
    D[1] += sv2 * (tmp[1] - c128z * sgv[1]);                                   \
    D[2] += sv2 * (tmp[2] - c128z * sgv[2]);                                   \
    D[3] += sv2 * (tmp[3] - c128z * sgv[3]);                                   \
  } while (0)

  for (int T = 0; T < 16; T += 2) {
    GBODY(T,     q0, a0, q1, a1);
    GBODY(T + 1, q1, a1, q0, a0);
  }
#undef GBODY

  *reinterpret_cast<f32x4*>(&red[wid][lane][0]) = D;
  __syncthreads();

  if (t < 128) {
    const int r = t >> 4, cc = t & 15;
    const int ln = (r >> 2) * 16 + cc, rg = r & 3;
    float v = red[0][ln][rg] + red[1][ln][rg] + red[2][ln][rg] + red[3][ln][rg];
    const int o = blockIdx.x * 16 + cc;
    v += (mode == 2) ? bF[o] : dec16(b16[o], mode);
    const size_t idx = (size_t)r * O_TOT + o;
    if (mode == 0)      ((__hip_bfloat16*)outv)[idx] = __float2bfloat16(v);
    else if (mode == 1) ((uint16_t*)outv)[idx] = f2h_bits(v);
    else                ((float*)outv)[idx] = v;
  }
}

static constexpr int NTHR = 512, O_PER_IT = 2, ITERS = 14, NBLK = 1024;
__global__ __launch_bounds__(NTHR, 1)
void wq_fallback_kernel(const uint16_t* __restrict__ x16,
                        const uint32_t* __restrict__ qweight,
                        const uint32_t* __restrict__ qzeros,
                        const uint16_t* __restrict__ sc16,
                        const uint16_t* __restrict__ b16,
                        void* __restrict__ outv,
                        const int* __restrict__ flag)
{
  __shared__ float lds[O_PER_IT][M_ROWS][NTHR];
  const int mode = *flag;
  const int t = threadIdx.x;
  const float* xF  = (const float*)x16;
  const float* scF = (const float*)sc16;
  const float* bF  = (const float*)b16;
  float xf[M_ROWS][16];
  {
    const int kbase = 16 * t;
    if (mode == 2) {
      #pragma unroll
      for (int n = 0; n < M_ROWS; ++n)
        #pragma unroll
        for (int i = 0; i < 16; ++i) xf[n][i] = xF[(size_t)n * K_TOT + kbase + i];
    } else {
      #pragma unroll
      for (int n = 0; n < M_ROWS; ++n)
        #pragma unroll
        for (int i = 0; i < 16; ++i) xf[n][i] = dec16(x16[(size_t)n * K_TOT + kbase + i], mode);
    }
  }
  const int g = t >> 3, zsh = (g & 7) * 4, zword = g >> 3;
  for (int it = 0; it < ITERS; ++it) {
    const int obase = blockIdx.x * (ITERS * O_PER_IT) + it * O_PER_IT;
    #pragma unroll
    for (int oi = 0; oi < O_PER_IT; ++oi) {
      const int o = obase + oi;
      const uint32_t zw = qzeros[o * 8 + zword];
      const float z = (float)((zw >> zsh) & 15u);
      const float s = (mode == 2) ? scF[o * 64 + g] : dec16(sc16[o * 64 + g], mode);
      const uint32_t w0 = qweight[(size_t)o * KW + 2 * t];
      const uint32_t w1 = qweight[(size_t)o * KW + 2 * t + 1];
      float d[M_ROWS];
      #pragma unroll
      for (int n = 0; n < M_ROWS; ++n) d[n] = 0.f;
      const uint32_t wvv[2] = { w0, w1 };
      #pragma unroll
      for (int w = 0; w < 2; ++w)
        #pragma unroll
        for (int j = 0; j < 8; ++j) {
          const float q = (float)((wvv[w] >> (4 * j)) & 15u);
          const float wgt = s * (q - z);
          #pragma unroll
          for (int n = 0; n < M_ROWS; ++n) d[n] = fmaf(wgt, xf[n][8 * w + j], d[n]);
        }
      #pragma unroll
      for (int n = 0; n < M_ROWS; ++n) lds[oi][n][t] = d[n];
    }
    __syncthreads();
    {
      const int wvid = t >> 6, lanei = t & 63;
      #pragma unroll
      for (int cc2 = 0; cc2 < 2; ++cc2) {
        const int p = 2 * wvid + cc2, oi = p >> 3, n = p & 7;
        float v = 0.f;
        #pragma unroll
        for (int i = 0; i < 8; ++i) v += lds[oi][n][lanei + 64 * i];
        v += __shfl_xor(v, 32); v += __shfl_xor(v, 16); v += __shfl_xor(v, 8);
        v += __shfl_xor(v, 4);  v += __shfl_xor(v, 2);  v += __shfl_xor(v, 1);
        if (lanei == 0) {
          const int o = obase + oi;
          const float b = (mode == 2) ? bF[o] : dec16(b16[o], mode);
          const float rr = v + b;
          const size_t idx = (size_t)n * O_TOT + o;
          if (mode == 0)      ((__hip_bfloat16*)outv)[idx] = __float2bfloat16(rr);
          else if (mode == 1) ((uint16_t*)outv)[idx] = f2h_bits(rr);
          else                ((float*)outv)[idx] = rr;
        }
      }
    }
    __syncthreads();
  }
}

extern "C" void kernel_launch(void* const* d_in, const int* in_sizes, int n_in,
                              void* d_out, int out_size, void* d_ws, size_t ws_size,
                              hipStream_t stream)
{
  const uint16_t* x       = (const uint16_t*)d_in[0];
  const uint32_t* qweight = (const uint32_t*)d_in[1];
  const uint32_t* qzeros  = (const uint32_t*)d_in[2];
  const uint16_t* scales  = (const uint16_t*)d_in[3];
  const uint16_t* bias    = (const uint16_t*)d_in[4];
  uint8_t* ws = (uint8_t*)d_ws;
  int* flag = (int*)d_ws;

  if (ws_size >= WS_NEED_V11) {
    float* part = (float*)(ws + WS_PART);
    hipLaunchKernelGGL(prep_fast_kernel, dim3(128), dim3(64), 0, stream, x, ws);
    hipLaunchKernelGGL(wq_mfma7_kernel, dim3(3584), dim3(256), 0, stream,
                       qweight, qzeros, scales, ws, part, flag);
    hipLaunchKernelGGL(reduce_kernel, dim3(224), dim3(256), 0, stream,
                       part, bias, d_out, flag);
  } else if (ws_size >= WS_NEED_R7) {
    hipLaunchKernelGGL(prep_fast_kernel, dim3(128), dim3(64), 0, stream, x, ws);
    hipLaunchKernelGGL(wq_mfma_kernel, dim3(1792), dim3(256), 0, stream,
                       qweight, qzeros, scales, bias, d_out, ws, flag);
  } else {
    hipLaunchKernelGGL(sniff_kernel, dim3(1), dim3(64), 0, stream, x, flag);
    hipLaunchKernelGGL(wq_fallback_kernel, dim3(NBLK), dim3(NTHR), 0, stream,
                       x, qweight, qzeros, scales, bias, d_out, flag);
  }
}